// Round 4
// baseline (790.948 us; speedup 1.0000x reference)
//
#include <hip/hip_runtime.h>
#include <stdint.h>

// VQ-VAE nearest-codebook index: N=32768 queries, D=64, K=8192 codes.
// Phase A: bf16x3 MFMA (hi/lo split), A-fragments split in-kernel from fp32,
//          B staged via global_load_lds DMA (16B). Split-K=4, 4 blocks/CU.
// Phase B: certified near-ties (gap < EPS_GAP) re-solved exactly in fp32.
// Numerics of phase A identical to validated round-3 kernel.

#define N_TOTAL 32768
#define K_CODES 8192
#define EPS_GAP 0.015f

typedef __attribute__((ext_vector_type(16))) float  floatx16;
typedef __attribute__((ext_vector_type(8)))  __bf16 bf16x8;

// ---- workspace layout (bytes) ----
#define O_C2    0u          // 8192 f32
#define O_CBSW  32768u      // [256 kBlk][16 cg][32 m][8 bf16] = 2 MB
#define O_PS1   2129920u    // 4*32768 f32
#define O_PS2   2654208u
#define O_PI1   3178496u
#define O_CNT   3702784u
#define O_LIST  3703040u    // 32768 int
#define O_SLOT  3834112u    // 32768 u64
#define WS_NEED 4096256u

__device__ __forceinline__ unsigned int fkey(float s) {
    unsigned int u = __float_as_uint(s);
    return (u & 0x80000000u) ? ~u : (u | 0x80000000u);
}

__device__ __forceinline__ void load_lds16(const void* g, void* l) {
    __builtin_amdgcn_global_load_lds(
        (const __attribute__((address_space(1))) unsigned int*)g,
        (__attribute__((address_space(3))) unsigned int*)l, 16, 0, 0);
}

// ---- prep: split codebook into hi/lo bf16 fragments + row norms + cnt=0 ----
__global__ __launch_bounds__(256) void vq_prep(
    const float4* __restrict__ cb, uint4* __restrict__ cbSw,
    float* __restrict__ c2, int* __restrict__ cnt) {
    __shared__ float red[256];
    const int m = threadIdx.x & 31, g = threadIdx.x >> 5;
    const int rb = blockIdx.x;
    if (rb == 0 && threadIdx.x == 0) *cnt = 0;
    float4 a = cb[(size_t)(rb * 32 + m) * 16 + g * 2];
    float4 b = cb[(size_t)(rb * 32 + m) * 16 + g * 2 + 1];
    float x[8] = {a.x, a.y, a.z, a.w, b.x, b.y, b.z, b.w};
    bf16x8 hv, lv;
    float ss = 0.f;
#pragma unroll
    for (int i = 0; i < 8; ++i) {
        float v  = x[i];
        __bf16 hb = (__bf16)v;           // RNE
        float r  = v - (float)hb;
        hv[i] = hb;
        lv[i] = (__bf16)r;
        ss += v * v;
    }
    cbSw[(size_t)rb * 512 + g * 32 + m]       = __builtin_bit_cast(uint4, hv);
    cbSw[(size_t)rb * 512 + (8 + g) * 32 + m] = __builtin_bit_cast(uint4, lv);
    red[threadIdx.x] = ss;
    __syncthreads();
    if (threadIdx.x < 32) {
        float s = 0.f;
#pragma unroll
        for (int gg = 0; gg < 8; ++gg) s += red[threadIdx.x + 32 * gg];
        c2[rb * 32 + threadIdx.x] = s;
    }
}

// ---- phase A: 128 queries x 2048 codes per block (split-K=4) ----
__global__ __launch_bounds__(256, 4) void vq_mfma(
    const float4* __restrict__ lat, const uint4* __restrict__ cbSw,
    const float* __restrict__ c2,
    float* __restrict__ pS1, float* __restrict__ pS2, int* __restrict__ pI1) {
    __shared__ uint4 Bs[2048];   // 32 KB: [4 kb][16 cg][32 m]
    const int tid = threadIdx.x;
    const int wr = tid >> 6, lane = tid & 63;
    const int m = lane & 31, h = lane >> 5;

    // A fragments: split in-kernel from raw fp32 (identical math to vq_prep).
    const int q = blockIdx.x * 128 + wr * 32 + m;
    bf16x8 aH[4], aL[4];
#pragma unroll
    for (int c = 0; c < 4; ++c) {
        float4 v0 = lat[(size_t)q * 16 + c * 4 + h * 2];
        float4 v1 = lat[(size_t)q * 16 + c * 4 + h * 2 + 1];
        float x[8] = {v0.x, v0.y, v0.z, v0.w, v1.x, v1.y, v1.z, v1.w};
#pragma unroll
        for (int j = 0; j < 8; ++j) {
            float v  = x[j];
            __bf16 hb = (__bf16)v;
            aH[c][j] = hb;
            aL[c][j] = (__bf16)(v - (float)hb);
        }
    }

    float s1[16], s2[16]; int i1[16];
#pragma unroll
    for (int r = 0; r < 16; ++r) { s1[r] = 3e38f; s2[r] = 3e38f; i1[r] = 0; }

    const int kBase = blockIdx.y * 2048;

    for (int stage = 0; stage < 16; ++stage) {
        const int rbBase = (kBase >> 5) + stage * 4;
        __syncthreads();
#pragma unroll
        for (int i = 0; i < 8; ++i)
            load_lds16(&cbSw[(size_t)rbBase * 512 + wr * 64 + 256 * i + lane],
                       &Bs[wr * 64 + 256 * i]);
        __syncthreads();

#pragma unroll
        for (int kb = 0; kb < 4; ++kb) {
            const int col = kBase + stage * 128 + kb * 32 + m;
            const float cc = c2[col];
            floatx16 acc;
#pragma unroll
            for (int r = 0; r < 16; ++r) acc[r] = 0.f;
#pragma unroll
            for (int c = 0; c < 4; ++c) {
                bf16x8 bH = __builtin_bit_cast(bf16x8, Bs[kb * 512 + (c * 2 + h) * 32 + m]);
                bf16x8 bL = __builtin_bit_cast(bf16x8, Bs[kb * 512 + (8 + c * 2 + h) * 32 + m]);
                acc = __builtin_amdgcn_mfma_f32_32x32x16_bf16(aH[c], bH, acc, 0, 0, 0);
                acc = __builtin_amdgcn_mfma_f32_32x32x16_bf16(aL[c], bH, acc, 0, 0, 0);
                acc = __builtin_amdgcn_mfma_f32_32x32x16_bf16(aH[c], bL, acc, 0, 0, 0);
            }
#pragma unroll
            for (int r = 0; r < 16; ++r) {
                float s = fmaf(-2.f, acc[r], cc);
                s2[r] = fminf(s2[r], fmaxf(s, s1[r]));
                bool lt = s < s1[r];
                i1[r] = lt ? col : i1[r];
                s1[r] = lt ? s : s1[r];
            }
        }
    }

    // reduce (s1,i1,s2) across the 32 column-lanes of each half
#pragma unroll
    for (int mask = 1; mask <= 16; mask <<= 1) {
#pragma unroll
        for (int r = 0; r < 16; ++r) {
            float o1 = __shfl_xor(s1[r], mask);
            float o2 = __shfl_xor(s2[r], mask);
            int   oi = __shfl_xor(i1[r], mask);
            float n2 = fminf(fminf(s2[r], o2), fmaxf(s1[r], o1));
            bool take = (o1 < s1[r]) || (o1 == s1[r] && oi < i1[r]);
            s1[r] = take ? o1 : s1[r];
            i1[r] = take ? oi : i1[r];
            s2[r] = n2;
        }
    }

    if (m == 0) {
        const int qb = blockIdx.x * 128 + wr * 32;
        const int o0 = blockIdx.y * N_TOTAL;
#pragma unroll
        for (int r = 0; r < 16; ++r) {
            int row = (r & 3) + 8 * (r >> 2) + 4 * h;   // C/D layout row
            int qq = qb + row;
            pS1[o0 + qq] = s1[r];
            pS2[o0 + qq] = s2[r];
            pI1[o0 + qq] = i1[r];
        }
    }
}

// ---- merge 4 split-K partitions, write indices, flag near-ties ----
__global__ void vq_merge4(const float* __restrict__ pS1, const float* __restrict__ pS2,
                          const int* __restrict__ pI1, int* __restrict__ out,
                          int* __restrict__ cnt, int* __restrict__ list,
                          unsigned long long* __restrict__ slot) {
    int q = blockIdx.x * 256 + threadIdx.x;
    float g1 = 3e38f, g2 = 3e38f;
    int   gi = 0x7FFFFFFF;
#pragma unroll
    for (int p = 0; p < 4; ++p) {
        float s1p = pS1[p * N_TOTAL + q];
        float s2p = pS2[p * N_TOTAL + q];
        int   i1p = pI1[p * N_TOTAL + q];
        bool take = (s1p < g1) || (s1p == g1 && i1p < gi);
        g2 = fminf(g2, fminf(s2p, take ? g1 : s1p));
        if (take) { g1 = s1p; gi = i1p; }
    }
    out[q] = gi;
    if (g2 - g1 < EPS_GAP) {
        int e = atomicAdd(cnt, 1);
        list[e] = q;
        slot[e] = 0xFFFFFFFFFFFFFFFFull;
    }
}

// ---- phase B: exact fp32, wave-parallel (query x 1024-code chunk) ----
__global__ __launch_bounds__(256) void vq_exact2(
    const float4* __restrict__ lat, const float4* __restrict__ cb,
    const float* __restrict__ c2, const int* __restrict__ cnt,
    const int* __restrict__ list, unsigned long long* __restrict__ slot) {
    __shared__ float qv[4][64];
    const int n = *cnt;
    const int totalChunks = n * 8;
    const int wInB = threadIdx.x >> 6;
    const int lane = threadIdx.x & 63;

    for (int base = blockIdx.x * 4; base < totalChunks; base += gridDim.x * 4) {
        const int c = base + wInB;
        const bool act = c < totalChunks;
        int e = 0, q = 0, kb = 0;
        if (act) { e = c >> 3; q = list[e]; kb = (c & 7) << 10; }
        __syncthreads();
        if (act && lane < 16) {
            float4 v = lat[(size_t)q * 16 + lane];
            *(float4*)&qv[wInB][lane * 4] = v;
        }
        __syncthreads();
        if (act) {
            float best = 3e38f; int bi = 0;
#pragma unroll 2
            for (int i = 0; i < 16; ++i) {
                const int k = kb + i * 64 + lane;
                float dot = 0.f;
#pragma unroll
                for (int d4 = 0; d4 < 16; ++d4) {
                    float4 cv = cb[(size_t)k * 16 + d4];
                    dot += qv[wInB][d4 * 4 + 0] * cv.x + qv[wInB][d4 * 4 + 1] * cv.y
                         + qv[wInB][d4 * 4 + 2] * cv.z + qv[wInB][d4 * 4 + 3] * cv.w;
                }
                float s = c2[k] - 2.f * dot;
                if (s < best) { best = s; bi = k; }
            }
            unsigned long long p = ((unsigned long long)fkey(best) << 32) | (unsigned)bi;
#pragma unroll
            for (int mask = 1; mask <= 32; mask <<= 1) {
                unsigned long long o = __shfl_xor(p, mask);
                p = o < p ? o : p;
            }
            if (lane == 0) atomicMin(&slot[e], p);
        }
    }
}

// ---- write back exact answers for flagged queries ----
__global__ void vq_write(const int* __restrict__ cnt, const int* __restrict__ list,
                         const unsigned long long* __restrict__ slot,
                         int* __restrict__ out) {
    int t = blockIdx.x * 256 + threadIdx.x;
    if (t < *cnt) out[list[t]] = (int)(slot[t] & 0xFFFFFFFFull);
}

// ================= fallback: validated round-1 fp32 path =================
#define BM 128
#define BN 128
#define PAD 68

__global__ void vq_norms_fb(const float4* __restrict__ cb, float* __restrict__ c2) {
    int t = blockIdx.x * 256 + threadIdx.x;
    int r = t >> 2, p = t & 3;
    float s = 0.f;
#pragma unroll
    for (int i = 0; i < 4; ++i) {
        float4 v = cb[r * 16 + p * 4 + i];
        s += v.x * v.x + v.y * v.y + v.z * v.z + v.w * v.w;
    }
    s += __shfl_xor(s, 1);
    s += __shfl_xor(s, 2);
    if (p == 0) c2[r] = s;
}

__global__ __launch_bounds__(256) void vq_fp32(
    const float4* __restrict__ lat, const float4* __restrict__ cb,
    const float* __restrict__ c2, int ktPer,
    int* __restrict__ outIdx, float* __restrict__ partS, int* __restrict__ partI,
    int writePartial) {
    __shared__ float As[BM][PAD];
    __shared__ float Bsf[BN][PAD];
    __shared__ float c2s[BN];
    const int tid = threadIdx.x;
    const int tx = tid & 15;
    const int ty = tid >> 4;
    const int nBase = blockIdx.x * BM;
    const int kt0 = blockIdx.y * ktPer;
    const int ktN = kt0 + ktPer;
#pragma unroll
    for (int r = 0; r < 8; ++r) {
        int f = tid + 256 * r;
        int mm = f >> 4, d4 = f & 15;
        float4 v = lat[(size_t)(nBase + mm) * 16 + d4];
        *(float4*)&As[mm][d4 * 4] = v;
    }
    float best[8]; int bidx[8];
#pragma unroll
    for (int ii = 0; ii < 8; ++ii) { best[ii] = 3e38f; bidx[ii] = 0; }
    for (int kt = kt0; kt < ktN; ++kt) {
        const int kbase = kt * BN;
        __syncthreads();
#pragma unroll
        for (int r = 0; r < 8; ++r) {
            int f = tid + 256 * r;
            int k = f >> 4, d4 = f & 15;
            float4 v = cb[(size_t)(kbase + k) * 16 + d4];
            *(float4*)&Bsf[k][d4 * 4] = v;
        }
        if (tid < BN) c2s[tid] = c2[kbase + tid];
        __syncthreads();
        float acc[8][8];
#pragma unroll
        for (int ii = 0; ii < 8; ++ii)
#pragma unroll
            for (int jj = 0; jj < 8; ++jj) acc[ii][jj] = 0.f;
#pragma unroll 4
        for (int d4 = 0; d4 < 16; ++d4) {
            float4 a[8], b[8];
#pragma unroll
            for (int ii = 0; ii < 8; ++ii) a[ii] = *(const float4*)&As[tx + 16 * ii][d4 * 4];
#pragma unroll
            for (int jj = 0; jj < 8; ++jj) b[jj] = *(const float4*)&Bsf[ty + 16 * jj][d4 * 4];
#pragma unroll
            for (int ii = 0; ii < 8; ++ii)
#pragma unroll
                for (int jj = 0; jj < 8; ++jj)
                    acc[ii][jj] += a[ii].x * b[jj].x + a[ii].y * b[jj].y
                                 + a[ii].z * b[jj].z + a[ii].w * b[jj].w;
        }
#pragma unroll
        for (int jj = 0; jj < 8; ++jj) {
            int k = kbase + ty + 16 * jj;
            float cc = c2s[ty + 16 * jj];
#pragma unroll
            for (int ii = 0; ii < 8; ++ii) {
                float s = cc - 2.f * acc[ii][jj];
                if (s < best[ii]) { best[ii] = s; bidx[ii] = k; }
            }
        }
    }
    __syncthreads();
    float* redS = &As[0][0];
    int*   redI = (int*)&Bsf[0][0];
#pragma unroll
    for (int ii = 0; ii < 8; ++ii) {
        int mm = tx + 16 * ii;
        redS[ty * BM + mm] = best[ii];
        redI[ty * BM + mm] = bidx[ii];
    }
    __syncthreads();
    if (tid < BM) {
        int mm = tid;
        float bs = redS[mm]; int bi = redI[mm];
#pragma unroll
        for (int t = 1; t < 16; ++t) {
            float s = redS[t * BM + mm]; int i = redI[t * BM + mm];
            if (s < bs || (s == bs && i < bi)) { bs = s; bi = i; }
        }
        int n = nBase + mm;
        if (writePartial) { partS[blockIdx.y * N_TOTAL + n] = bs; partI[blockIdx.y * N_TOTAL + n] = bi; }
        else outIdx[n] = bi;
    }
}

__global__ void vq_merge_fb(const float* __restrict__ partS, const int* __restrict__ partI,
                            int* __restrict__ out) {
    int n = blockIdx.x * 256 + threadIdx.x;
    float s0 = partS[n], s1 = partS[N_TOTAL + n];
    int   i0 = partI[n], i1 = partI[N_TOTAL + n];
    out[n] = (s1 < s0) ? i1 : i0;
}

extern "C" void kernel_launch(void* const* d_in, const int* in_sizes, int n_in,
                              void* d_out, int out_size, void* d_ws, size_t ws_size,
                              hipStream_t stream) {
    const float4* lat = (const float4*)d_in[0];
    const float4* cb  = (const float4*)d_in[1];
    int* out = (int*)d_out;
    char* ws = (char*)d_ws;

    if (ws_size >= WS_NEED) {
        float* c2   = (float*)(ws + O_C2);
        uint4* cbSw = (uint4*)(ws + O_CBSW);
        float* pS1  = (float*)(ws + O_PS1);
        float* pS2  = (float*)(ws + O_PS2);
        int*   pI1  = (int*)(ws + O_PI1);
        int*   cnt  = (int*)(ws + O_CNT);
        int*   list = (int*)(ws + O_LIST);
        unsigned long long* slot = (unsigned long long*)(ws + O_SLOT);

        vq_prep<<<256, 256, 0, stream>>>(cb, cbSw, c2, cnt);
        vq_mfma<<<dim3(256, 4), 256, 0, stream>>>(lat, cbSw, c2, pS1, pS2, pI1);
        vq_merge4<<<128, 256, 0, stream>>>(pS1, pS2, pI1, out, cnt, list, slot);
        vq_exact2<<<1024, 256, 0, stream>>>(lat, cb, c2, cnt, list, slot);
        vq_write<<<128, 256, 0, stream>>>(cnt, list, slot, out);
    } else {
        float* c2 = (float*)ws;
        vq_norms_fb<<<128, 256, 0, stream>>>(cb, c2);
        const size_t needSplit = 32768u + 2u * N_TOTAL * 4u + 2u * N_TOTAL * 4u + 64u;
        if (ws_size >= needSplit) {
            float* partS = (float*)(ws + 32768);
            int*   partI = (int*)(ws + 32768 + 2 * N_TOTAL * 4);
            dim3 grid(N_TOTAL / BM, 2);
            vq_fp32<<<grid, 256, 0, stream>>>(lat, cb, c2, (K_CODES / BN) / 2, out, partS, partI, 1);
            vq_merge_fb<<<N_TOTAL / 256, 256, 0, stream>>>(partS, partI, out);
        } else {
            dim3 grid(N_TOTAL / BM, 1);
            vq_fp32<<<grid, 256, 0, stream>>>(lat, cb, c2, K_CODES / BN, out, nullptr, nullptr, 0);
        }
    }
}

// Round 6
// 246.335 us; speedup vs baseline: 3.2109x; 3.2109x over previous
//
#include <hip/hip_runtime.h>
#include <stdint.h>

// VQ-VAE nearest-codebook index: N=32768 queries, D=64, K=8192 codes.
// Phase A: bf16x3 MFMA (hi/lo split), A-fragments split in-kernel from fp32,
//          B staged via global_load_lds DMA (16B). Split-K=4.
//          Per-query best + second-best (s2) tracking -- the R3/R4-proven
//          certification. (R5's flag-bitmask over-flagged ~20k queries and
//          showed a post-timing divergence; reverted wholesale.)
// Phase B: queries with s2-s1 < EPS_GAP re-solved exactly in fp32.
// launch_bounds(256,2): cap 256 VGPR. R4's (256,4) cap=128 forced scratch
// spills (WRITE_SIZE 1.29 GB, 689us); natural usage ~150 VGPR -> 3 blocks/CU.

#define N_TOTAL 32768
#define K_CODES 8192
#define EPS_GAP 0.015f

typedef __attribute__((ext_vector_type(16))) float  floatx16;
typedef __attribute__((ext_vector_type(8)))  __bf16 bf16x8;

// ---- workspace layout (bytes) ----
#define O_C2    0u          // 8192 f32
#define O_CBSW  32768u      // [256 kBlk][16 cg][32 m][8 bf16] = 2 MB
#define O_PS1   2129920u    // 4*32768 f32
#define O_PS2   2654208u    // 4*32768 f32
#define O_PI1   3178496u    // 4*32768 i32
#define O_CNT   3702784u
#define O_LIST  3703040u    // 32768 int
#define O_SLOT  3834112u    // 32768 u64
#define WS_NEED 4096256u

__device__ __forceinline__ unsigned int fkey(float s) {
    unsigned int u = __float_as_uint(s);
    return (u & 0x80000000u) ? ~u : (u | 0x80000000u);
}

__device__ __forceinline__ void load_lds16(const void* g, void* l) {
    __builtin_amdgcn_global_load_lds(
        (const __attribute__((address_space(1))) unsigned int*)g,
        (__attribute__((address_space(3))) unsigned int*)l, 16, 0, 0);
}

// ---- prep: split codebook into hi/lo bf16 fragments + row norms + cnt=0 ----
__global__ __launch_bounds__(256) void vq_prep(
    const float4* __restrict__ cb, uint4* __restrict__ cbSw,
    float* __restrict__ c2, int* __restrict__ cnt) {
    __shared__ float red[256];
    const int m = threadIdx.x & 31, g = threadIdx.x >> 5;
    const int rb = blockIdx.x;
    if (rb == 0 && threadIdx.x == 0) *cnt = 0;
    float4 a = cb[(size_t)(rb * 32 + m) * 16 + g * 2];
    float4 b = cb[(size_t)(rb * 32 + m) * 16 + g * 2 + 1];
    float x[8] = {a.x, a.y, a.z, a.w, b.x, b.y, b.z, b.w};
    bf16x8 hv, lv;
    float ss = 0.f;
#pragma unroll
    for (int i = 0; i < 8; ++i) {
        float v  = x[i];
        __bf16 hb = (__bf16)v;           // RNE
        float r  = v - (float)hb;
        hv[i] = hb;
        lv[i] = (__bf16)r;
        ss += v * v;
    }
    cbSw[(size_t)rb * 512 + g * 32 + m]       = __builtin_bit_cast(uint4, hv);
    cbSw[(size_t)rb * 512 + (8 + g) * 32 + m] = __builtin_bit_cast(uint4, lv);
    red[threadIdx.x] = ss;
    __syncthreads();
    if (threadIdx.x < 32) {
        float s = 0.f;
#pragma unroll
        for (int gg = 0; gg < 8; ++gg) s += red[threadIdx.x + 32 * gg];
        c2[rb * 32 + threadIdx.x] = s;
    }
}

// ---- phase A: 128 queries x 2048 codes per block (split-K=4) ----
__global__ __launch_bounds__(256, 2) void vq_mfma(
    const float4* __restrict__ lat, const uint4* __restrict__ cbSw,
    const float* __restrict__ c2,
    float* __restrict__ pS1, float* __restrict__ pS2, int* __restrict__ pI1) {
    __shared__ uint4 Bs[2048];   // 32 KB: [4 kb][16 cg][32 m]
    const int tid = threadIdx.x;
    const int wr = tid >> 6, lane = tid & 63;
    const int m = lane & 31, h = lane >> 5;

    // A fragments: split in-kernel from raw fp32 (identical math to vq_prep).
    const int q = blockIdx.x * 128 + wr * 32 + m;
    bf16x8 aH[4], aL[4];
#pragma unroll
    for (int c = 0; c < 4; ++c) {
        float4 v0 = lat[(size_t)q * 16 + c * 4 + h * 2];
        float4 v1 = lat[(size_t)q * 16 + c * 4 + h * 2 + 1];
        float x[8] = {v0.x, v0.y, v0.z, v0.w, v1.x, v1.y, v1.z, v1.w};
#pragma unroll
        for (int j = 0; j < 8; ++j) {
            float v  = x[j];
            __bf16 hb = (__bf16)v;
            aH[c][j] = hb;
            aL[c][j] = (__bf16)(v - (float)hb);
        }
    }

    float s1[16], s2[16]; int i1[16];
#pragma unroll
    for (int r = 0; r < 16; ++r) { s1[r] = 3e38f; s2[r] = 3e38f; i1[r] = 0; }

    const int kBase = blockIdx.y * 2048;

    for (int stage = 0; stage < 16; ++stage) {
        const int rbBase = (kBase >> 5) + stage * 4;
        __syncthreads();
#pragma unroll
        for (int i = 0; i < 8; ++i)
            load_lds16(&cbSw[(size_t)rbBase * 512 + wr * 64 + 256 * i + lane],
                       &Bs[wr * 64 + 256 * i]);
        __syncthreads();

#pragma unroll
        for (int kb = 0; kb < 4; ++kb) {
            const int col = kBase + stage * 128 + kb * 32 + m;
            const float cc = c2[col];
            floatx16 acc;
#pragma unroll
            for (int r = 0; r < 16; ++r) acc[r] = 0.f;
#pragma unroll
            for (int c = 0; c < 4; ++c) {
                bf16x8 bH = __builtin_bit_cast(bf16x8, Bs[kb * 512 + (c * 2 + h) * 32 + m]);
                bf16x8 bL = __builtin_bit_cast(bf16x8, Bs[kb * 512 + (8 + c * 2 + h) * 32 + m]);
                acc = __builtin_amdgcn_mfma_f32_32x32x16_bf16(aH[c], bH, acc, 0, 0, 0);
                acc = __builtin_amdgcn_mfma_f32_32x32x16_bf16(aL[c], bH, acc, 0, 0, 0);
                acc = __builtin_amdgcn_mfma_f32_32x32x16_bf16(aH[c], bL, acc, 0, 0, 0);
            }
#pragma unroll
            for (int r = 0; r < 16; ++r) {
                float s = fmaf(-2.f, acc[r], cc);
                s2[r] = fminf(s2[r], fmaxf(s, s1[r]));
                bool lt = s < s1[r];
                i1[r] = lt ? col : i1[r];
                s1[r] = lt ? s : s1[r];
            }
        }
    }

    // reduce (s1,i1,s2) across the 32 column-lanes of each half
#pragma unroll
    for (int mask = 1; mask <= 16; mask <<= 1) {
#pragma unroll
        for (int r = 0; r < 16; ++r) {
            float o1 = __shfl_xor(s1[r], mask);
            float o2 = __shfl_xor(s2[r], mask);
            int   oi = __shfl_xor(i1[r], mask);
            float n2 = fminf(fminf(s2[r], o2), fmaxf(s1[r], o1));
            bool take = (o1 < s1[r]) || (o1 == s1[r] && oi < i1[r]);
            s1[r] = take ? o1 : s1[r];
            i1[r] = take ? oi : i1[r];
            s2[r] = n2;
        }
    }

    if (m == 0) {
        const int qb = blockIdx.x * 128 + wr * 32;
        const int o0 = blockIdx.y * N_TOTAL;
#pragma unroll
        for (int r = 0; r < 16; ++r) {
            int row = (r & 3) + 8 * (r >> 2) + 4 * h;   // C/D layout row
            int qq = qb + row;
            pS1[o0 + qq] = s1[r];
            pS2[o0 + qq] = s2[r];
            pI1[o0 + qq] = i1[r];
        }
    }
}

// ---- merge 4 split-K partitions, write indices, flag near-ties ----
__global__ void vq_merge4(const float* __restrict__ pS1, const float* __restrict__ pS2,
                          const int* __restrict__ pI1, int* __restrict__ out,
                          int* __restrict__ cnt, int* __restrict__ list,
                          unsigned long long* __restrict__ slot) {
    int q = blockIdx.x * 256 + threadIdx.x;
    float g1 = 3e38f, g2 = 3e38f;
    int   gi = 0x7FFFFFFF;
#pragma unroll
    for (int p = 0; p < 4; ++p) {
        float s1p = pS1[p * N_TOTAL + q];
        float s2p = pS2[p * N_TOTAL + q];
        int   i1p = pI1[p * N_TOTAL + q];
        bool take = (s1p < g1) || (s1p == g1 && i1p < gi);
        g2 = fminf(g2, fminf(s2p, take ? g1 : s1p));
        if (take) { g1 = s1p; gi = i1p; }
    }
    out[q] = gi;
    if (g2 - g1 < EPS_GAP) {
        int e = atomicAdd(cnt, 1);
        list[e] = q;
        slot[e] = 0xFFFFFFFFFFFFFFFFull;
    }
}

// ---- phase B: exact fp32, wave-parallel (query x 1024-code chunk) ----
__global__ __launch_bounds__(256) void vq_exact2(
    const float4* __restrict__ lat, const float4* __restrict__ cb,
    const float* __restrict__ c2, const int* __restrict__ cnt,
    const int* __restrict__ list, unsigned long long* __restrict__ slot) {
    __shared__ float qv[4][64];
    const int n = *cnt;
    const int totalChunks = n * 8;
    const int wInB = threadIdx.x >> 6;
    const int lane = threadIdx.x & 63;

    for (int base = blockIdx.x * 4; base < totalChunks; base += gridDim.x * 4) {
        const int c = base + wInB;
        const bool act = c < totalChunks;
        int e = 0, q = 0, kb = 0;
        if (act) { e = c >> 3; q = list[e]; kb = (c & 7) << 10; }
        __syncthreads();
        if (act && lane < 16) {
            float4 v = lat[(size_t)q * 16 + lane];
            *(float4*)&qv[wInB][lane * 4] = v;
        }
        __syncthreads();
        if (act) {
            float best = 3e38f; int bi = 0;
#pragma unroll 2
            for (int i = 0; i < 16; ++i) {
                const int k = kb + i * 64 + lane;
                float dot = 0.f;
#pragma unroll
                for (int d4 = 0; d4 < 16; ++d4) {
                    float4 cv = cb[(size_t)k * 16 + d4];
                    dot += qv[wInB][d4 * 4 + 0] * cv.x + qv[wInB][d4 * 4 + 1] * cv.y
                         + qv[wInB][d4 * 4 + 2] * cv.z + qv[wInB][d4 * 4 + 3] * cv.w;
                }
                float s = c2[k] - 2.f * dot;
                if (s < best) { best = s; bi = k; }
            }
            unsigned long long p = ((unsigned long long)fkey(best) << 32) | (unsigned)bi;
#pragma unroll
            for (int mask = 1; mask <= 32; mask <<= 1) {
                unsigned long long o = __shfl_xor(p, mask);
                p = o < p ? o : p;
            }
            if (lane == 0) atomicMin(&slot[e], p);
        }
    }
}

// ---- write back exact answers for flagged queries ----
__global__ void vq_write(const int* __restrict__ cnt, const int* __restrict__ list,
                         const unsigned long long* __restrict__ slot,
                         int* __restrict__ out) {
    int t = blockIdx.x * 256 + threadIdx.x;
    if (t < *cnt) out[list[t]] = (int)(slot[t] & 0xFFFFFFFFull);
}

// ================= fallback: validated round-1 fp32 path =================
#define BM 128
#define BN 128
#define PAD 68

__global__ void vq_norms_fb(const float4* __restrict__ cb, float* __restrict__ c2) {
    int t = blockIdx.x * 256 + threadIdx.x;
    int r = t >> 2, p = t & 3;
    float s = 0.f;
#pragma unroll
    for (int i = 0; i < 4; ++i) {
        float4 v = cb[r * 16 + p * 4 + i];
        s += v.x * v.x + v.y * v.y + v.z * v.z + v.w * v.w;
    }
    s += __shfl_xor(s, 1);
    s += __shfl_xor(s, 2);
    if (p == 0) c2[r] = s;
}

__global__ __launch_bounds__(256) void vq_fp32(
    const float4* __restrict__ lat, const float4* __restrict__ cb,
    const float* __restrict__ c2, int ktPer,
    int* __restrict__ outIdx, float* __restrict__ partS, int* __restrict__ partI,
    int writePartial) {
    __shared__ float As[BM][PAD];
    __shared__ float Bsf[BN][PAD];
    __shared__ float c2s[BN];
    const int tid = threadIdx.x;
    const int tx = tid & 15;
    const int ty = tid >> 4;
    const int nBase = blockIdx.x * BM;
    const int kt0 = blockIdx.y * ktPer;
    const int ktN = kt0 + ktPer;
#pragma unroll
    for (int r = 0; r < 8; ++r) {
        int f = tid + 256 * r;
        int mm = f >> 4, d4 = f & 15;
        float4 v = lat[(size_t)(nBase + mm) * 16 + d4];
        *(float4*)&As[mm][d4 * 4] = v;
    }
    float best[8]; int bidx[8];
#pragma unroll
    for (int ii = 0; ii < 8; ++ii) { best[ii] = 3e38f; bidx[ii] = 0; }
    for (int kt = kt0; kt < ktN; ++kt) {
        const int kbase = kt * BN;
        __syncthreads();
#pragma unroll
        for (int r = 0; r < 8; ++r) {
            int f = tid + 256 * r;
            int k = f >> 4, d4 = f & 15;
            float4 v = cb[(size_t)(kbase + k) * 16 + d4];
            *(float4*)&Bsf[k][d4 * 4] = v;
        }
        if (tid < BN) c2s[tid] = c2[kbase + tid];
        __syncthreads();
        float acc[8][8];
#pragma unroll
        for (int ii = 0; ii < 8; ++ii)
#pragma unroll
            for (int jj = 0; jj < 8; ++jj) acc[ii][jj] = 0.f;
#pragma unroll 4
        for (int d4 = 0; d4 < 16; ++d4) {
            float4 a[8], b[8];
#pragma unroll
            for (int ii = 0; ii < 8; ++ii) a[ii] = *(const float4*)&As[tx + 16 * ii][d4 * 4];
#pragma unroll
            for (int jj = 0; jj < 8; ++jj) b[jj] = *(const float4*)&Bsf[ty + 16 * jj][d4 * 4];
#pragma unroll
            for (int ii = 0; ii < 8; ++ii)
#pragma unroll
                for (int jj = 0; jj < 8; ++jj)
                    acc[ii][jj] += a[ii].x * b[jj].x + a[ii].y * b[jj].y
                                 + a[ii].z * b[jj].z + a[ii].w * b[jj].w;
        }
#pragma unroll
        for (int jj = 0; jj < 8; ++jj) {
            int k = kbase + ty + 16 * jj;
            float cc = c2s[ty + 16 * jj];
#pragma unroll
            for (int ii = 0; ii < 8; ++ii) {
                float s = cc - 2.f * acc[ii][jj];
                if (s < best[ii]) { best[ii] = s; bidx[ii] = k; }
            }
        }
    }
    __syncthreads();
    float* redS = &As[0][0];
    int*   redI = (int*)&Bsf[0][0];
#pragma unroll
    for (int ii = 0; ii < 8; ++ii) {
        int mm = tx + 16 * ii;
        redS[ty * BM + mm] = best[ii];
        redI[ty * BM + mm] = bidx[ii];
    }
    __syncthreads();
    if (tid < BM) {
        int mm = tid;
        float bs = redS[mm]; int bi = redI[mm];
#pragma unroll
        for (int t = 1; t < 16; ++t) {
            float s = redS[t * BM + mm]; int i = redI[t * BM + mm];
            if (s < bs || (s == bs && i < bi)) { bs = s; bi = i; }
        }
        int n = nBase + mm;
        if (writePartial) { partS[blockIdx.y * N_TOTAL + n] = bs; partI[blockIdx.y * N_TOTAL + n] = bi; }
        else outIdx[n] = bi;
    }
}

__global__ void vq_merge_fb(const float* __restrict__ partS, const int* __restrict__ partI,
                            int* __restrict__ out) {
    int n = blockIdx.x * 256 + threadIdx.x;
    float s0 = partS[n], s1 = partS[N_TOTAL + n];
    int   i0 = partI[n], i1 = partI[N_TOTAL + n];
    out[n] = (s1 < s0) ? i1 : i0;
}

extern "C" void kernel_launch(void* const* d_in, const int* in_sizes, int n_in,
                              void* d_out, int out_size, void* d_ws, size_t ws_size,
                              hipStream_t stream) {
    const float4* lat = (const float4*)d_in[0];
    const float4* cb  = (const float4*)d_in[1];
    int* out = (int*)d_out;
    char* ws = (char*)d_ws;

    if (ws_size >= WS_NEED) {
        float* c2   = (float*)(ws + O_C2);
        uint4* cbSw = (uint4*)(ws + O_CBSW);
        float* pS1  = (float*)(ws + O_PS1);
        float* pS2  = (float*)(ws + O_PS2);
        int*   pI1  = (int*)(ws + O_PI1);
        int*   cnt  = (int*)(ws + O_CNT);
        int*   list = (int*)(ws + O_LIST);
        unsigned long long* slot = (unsigned long long*)(ws + O_SLOT);

        vq_prep<<<256, 256, 0, stream>>>(cb, cbSw, c2, cnt);
        vq_mfma<<<dim3(256, 4), 256, 0, stream>>>(lat, cbSw, c2, pS1, pS2, pI1);
        vq_merge4<<<128, 256, 0, stream>>>(pS1, pS2, pI1, out, cnt, list, slot);
        vq_exact2<<<1024, 256, 0, stream>>>(lat, cb, c2, cnt, list, slot);
        vq_write<<<128, 256, 0, stream>>>(cnt, list, slot, out);
    } else {
        float* c2 = (float*)ws;
        vq_norms_fb<<<128, 256, 0, stream>>>(cb, c2);
        const size_t needSplit = 32768u + 2u * N_TOTAL * 4u + 2u * N_TOTAL * 4u + 64u;
        if (ws_size >= needSplit) {
            float* partS = (float*)(ws + 32768);
            int*   partI = (int*)(ws + 32768 + 2 * N_TOTAL * 4);
            dim3 grid(N_TOTAL / BM, 2);
            vq_fp32<<<grid, 256, 0, stream>>>(lat, cb, c2, (K_CODES / BN) / 2, out, partS, partI, 1);
            vq_merge_fb<<<N_TOTAL / 256, 256, 0, stream>>>(partS, partI, out);
        } else {
            dim3 grid(N_TOTAL / BM, 1);
            vq_fp32<<<grid, 256, 0, stream>>>(lat, cb, c2, K_CODES / BN, out, nullptr, nullptr, 0);
        }
    }
}